// Round 20
// baseline (371.394 us; speedup 1.0000x reference)
//
#include <hip/hip_runtime.h>
#include <cfloat>
#include <math.h>

#define B_ 8
#define N_ 4096
#define F_ 64
#define O_ 64
#define K_ 20
#define NSEL 20       // per-owner kept; NSEL >= K_ REQUIRED for exactness (R11 post-mortem)
#define CAND 24       // emitted after 8-way merge
#define NOWN 8
#define ITILE 64      // i-rows per block (co-residency invariant: grid 512, 2 blocks/CU)
#define JCH 128       // j-chunk per iteration
#define BSTR 72       // ushort stride of staged rows
#define QSTR 172      // rowq stride (==12 mod 32); >= 168 for sorted dump
#define SSTR 21       // sorted-dump stride per owner (20 + sentinel)

typedef __attribute__((ext_vector_type(8))) short bf16x8;
typedef __attribute__((ext_vector_type(16))) float f32x16;

__device__ __forceinline__ ushort f2bf(float f) {
  unsigned u = __float_as_uint(f);
  u += 0x7FFF + ((u >> 16) & 1);   // round-to-nearest-even
  return (ushort)(u >> 16);
}

// ---------------- K1: feat + fused bf16 convert + squared norms + sums zero ----------------
__global__ __launch_bounds__(256) void feat_kernel(const float* __restrict__ x,
                                                   const float* __restrict__ W,
                                                   float* __restrict__ A,
                                                   float* __restrict__ C,
                                                   ushort* __restrict__ xhi,
                                                   float* __restrict__ sq,
                                                   float* __restrict__ sums) {
  if (blockIdx.x == 0 && threadIdx.x < 128) sums[threadIdx.x] = 0.f;  // zero BN accumulators
  __shared__ float xs[16][64];
  const int nb = blockIdx.x * 16;
  {
    int row = threadIdx.x >> 4, f4 = threadIdx.x & 15;
    float4 v = ((const float4*)(x + (size_t)(nb + row) * F_))[f4];
    *(float4*)&xs[row][f4 * 4] = v;
    ((ushort4*)(xhi + (size_t)(nb + row) * F_))[f4] =
        make_ushort4(f2bf(v.x), f2bf(v.y), f2bf(v.z), f2bf(v.w));
    float s = v.x * v.x + v.y * v.y + v.z * v.z + v.w * v.w;
#pragma unroll
    for (int off = 1; off < 16; off <<= 1) s += __shfl_xor(s, off, 64);
    if (f4 == 0) sq[nb + row] = s;
  }
  __syncthreads();
  const int o = threadIdx.x & 127;
  const int rgrp = threadIdx.x >> 7;
  if (o < O_) {
    float wd[64];
    const float4* w1 = (const float4*)(W + (size_t)o * 128);
    const float4* w2 = w1 + 16;
#pragma unroll
    for (int f = 0; f < 16; ++f) {
      float4 u = w1[f], v = w2[f];
      wd[4 * f] = u.x - v.x; wd[4 * f + 1] = u.y - v.y;
      wd[4 * f + 2] = u.z - v.z; wd[4 * f + 3] = u.w - v.w;
    }
#pragma unroll
    for (int r = 0; r < 8; ++r) {
      int row = rgrp * 8 + r;
      float a0 = 0.f, a1 = 0.f;
#pragma unroll
      for (int f = 0; f < 32; ++f) {
        a0 = fmaf(xs[row][2 * f], wd[2 * f], a0);
        a1 = fmaf(xs[row][2 * f + 1], wd[2 * f + 1], a1);
      }
      A[(size_t)(nb + row) * O_ + o] = a0 + a1;
    }
  } else {
    float wv[64];
    const float4* w2 = (const float4*)(W + (size_t)(o - O_) * 128 + 64);
#pragma unroll
    for (int f = 0; f < 16; ++f) {
      float4 v = w2[f];
      wv[4 * f] = v.x; wv[4 * f + 1] = v.y; wv[4 * f + 2] = v.z; wv[4 * f + 3] = v.w;
    }
#pragma unroll
    for (int r = 0; r < 8; ++r) {
      int row = rgrp * 8 + r;
      float a0 = 0.f, a1 = 0.f;
#pragma unroll
      for (int f = 0; f < 32; ++f) {
        a0 = fmaf(xs[row][2 * f], wv[2 * f], a0);
        a1 = fmaf(xs[row][2 * f + 1], wv[2 * f + 1], a1);
      }
      C[(size_t)(nb + row) * O_ + (o - O_)] = a0 + a1;
    }
  }
}

// ---------------- K2: kNN — byte-identical to R19 (measured 170 us) ----------------
struct KnnSh {
  ushort bhi[JCH][BSTR];      // 18432 B
  float  sqj[JCH];            // 512 B
  float  rowq[ITILE * QSTR];  // 44032 B
  int qcnt[ITILE];
  alignas(16) int thr[ITILE]; // 16B-aligned for b128 hoist
};                            // ~63.5 KB -> 2 blocks/CU (all 512 blocks co-resident)

__global__ __launch_bounds__(512, 4) void knn_kernel(const ushort* __restrict__ xhi,
                                                     const float* __restrict__ sq,
                                                     int* __restrict__ cand) {
  __shared__ KnnSh S;

  const int b = blockIdx.x >> 6;             // L2-proven mapping
  const int ib = (blockIdx.x & 63) * ITILE;  // batch-local i base
  const int tid = threadIdx.x;
  const int w = tid >> 6, lane = tid & 63;
  const int l31 = lane & 31, lh = lane >> 5;
  const int h = w & 1;                       // i-half
  const int jcol = (w >> 1) * 32;            // j-quarter

  bf16x8 ah[4];
  {
    const size_t ar = ((size_t)b * N_ + ib + h * 32 + l31) * F_ + lh * 8;
#pragma unroll
    for (int kk = 0; kk < 4; ++kk) ah[kk] = *(const bf16x8*)(xhi + ar + kk * 16);
  }
  float sqi[16];
#pragma unroll
  for (int r = 0; r < 16; ++r)
    sqi[r] = sq[b * N_ + ib + h * 32 + (r & 3) + 8 * (r >> 2) + 4 * lh];

  if (tid < ITILE) S.thr[tid] = 0x7F7F0000;

  const int orow = tid >> 3, oslot = tid & 7;   // 8 owners per row
  float d[NSEL];
#pragma unroll
  for (int k = 0; k < NSEL; ++k) d[k] = __int_as_float(0x7F7E0000 | k);
  float mx = __int_as_float(0x7F7E0000 | (NSEL - 1));

  const int selfchunk = ib & ~(JCH - 1);

  for (int jt = 0; jt < N_; jt += JCH) {
    __syncthreads();   // prev owner phase done; thr updates visible
    const bool dense = (jt < 2 * JCH);
    if (tid < ITILE) S.qcnt[tid] = dense ? JCH : 0;

    int4 thrq[4];
#pragma unroll
    for (int g = 0; g < 4; ++g)
      thrq[g] = *(const int4*)&S.thr[h * 32 + 4 * lh + 8 * g];

#pragma unroll
    for (int u = 0; u < 2; ++u) {
      int idx = tid + u * 512;
      int jr = idx >> 3, fc = (idx & 7) * 8;
      *(bf16x8*)&S.bhi[jr][fc] =
          *(const bf16x8*)(xhi + ((size_t)b * N_ + jt + jr) * F_ + fc);
    }
    if (tid < JCH) S.sqj[tid] = sq[b * N_ + jt + tid];
    __syncthreads();

    const ushort* bp = &S.bhi[jcol + l31][lh * 8];
    bf16x8 bf[4];
#pragma unroll
    for (int kk = 0; kk < 4; ++kk) bf[kk] = *(const bf16x8*)(bp + kk * 16);

    const int jg = jt + jcol + l31;              // batch-local j
    const float sqjv = S.sqj[jcol + l31];
    const bool selfc = (jt == selfchunk);

    f32x16 c = {0.f, 0.f, 0.f, 0.f, 0.f, 0.f, 0.f, 0.f,
                0.f, 0.f, 0.f, 0.f, 0.f, 0.f, 0.f, 0.f};
#pragma unroll
    for (int kk = 0; kk < 4; ++kk)
      c = __builtin_amdgcn_mfma_f32_32x32x16_bf16(ah[kk], bf[kk], c, 0, 0, 0);
#pragma unroll
    for (int r = 0; r < 16; ++r) {
      const int ir = h * 32 + (r & 3) + 8 * (r >> 2) + 4 * lh;  // local i-row
      float dd = fmaf(-2.f, c[r], sqi[r] + sqjv);
      float pv = __int_as_float((__float_as_int(dd) & (int)0xFFFFF000) | jg);
      if (selfc && (ib + ir == jg)) pv = __int_as_float(0x7F500000 | jg);
      if (dense) {
        S.rowq[ir * QSTR + (jcol + l31)] = pv;
      } else if (pv < __int_as_float(((const int*)&thrq[r >> 2])[r & 3])) {
        int pos = atomicAdd(&S.qcnt[ir], 1);
        S.rowq[ir * QSTR + pos] = pv;
      }
    }
    __syncthreads();

    {
      int cn = S.qcnt[orow];
      for (int q = oslot; q < cn; q += NOWN) {
        float pv = S.rowq[orow * QSTR + q];
        if (pv < mx) {
#pragma unroll
          for (int k = 0; k < NSEL; ++k) d[k] = (d[k] == mx) ? pv : d[k];
          float t0[10];
#pragma unroll
          for (int k = 0; k < 10; ++k) t0[k] = fmaxf(d[2 * k], d[2 * k + 1]);
#pragma unroll
          for (int k = 0; k < 5; ++k) t0[k] = fmaxf(t0[2 * k], (k < 4) ? t0[2 * k + 1] : t0[9]);
          mx = fmaxf(fmaxf(fmaxf(t0[0], t0[1]), fmaxf(t0[2], t0[3])), t0[4]);
        }
      }
      atomicMin(&S.thr[orow], __float_as_int(mx));
    }
  }

  __syncthreads();  // queue dead; reuse rowq for sorted dump
  float a32[32];
#pragma unroll
  for (int k = 0; k < NSEL; ++k) a32[k] = d[k];
#pragma unroll
  for (int k = NSEL; k < 32; ++k) a32[k] = __int_as_float(0x7F7E0000 | k);
#pragma unroll
  for (int kk = 2; kk <= 32; kk <<= 1) {
#pragma unroll
    for (int jj = kk >> 1; jj > 0; jj >>= 1) {
#pragma unroll
      for (int ii = 0; ii < 32; ++ii) {
        int ll = ii ^ jj;
        if (ll > ii) {
          bool up = ((ii & kk) == 0);
          float av = a32[ii], bv = a32[ll];
          float lo = fminf(av, bv), hi = fmaxf(av, bv);
          a32[ii] = up ? lo : hi;
          a32[ll] = up ? hi : lo;
        }
      }
    }
  }
#pragma unroll
  for (int k = 0; k < NSEL; ++k)
    S.rowq[orow * QSTR + oslot * SSTR + k] = a32[k];
  S.rowq[orow * QSTR + oslot * SSTR + NSEL] = __int_as_float(0x7F700000);
  __syncthreads();

  if (tid < ITILE) {
    const float* base = &S.rowq[tid * QSTR];
    int* crow = cand + (size_t)(b * N_ + ib + tid) * CAND;
    int p0 = 0, p1 = 0, p2 = 0, p3 = 0, p4 = 0, p5 = 0, p6 = 0, p7 = 0;
    for (int k = 0; k < CAND; ++k) {
      float hv = base[p0]; int sm = 0;
      float t;
      t = base[SSTR + p1];     if (t < hv) { hv = t; sm = 1; }
      t = base[2 * SSTR + p2]; if (t < hv) { hv = t; sm = 2; }
      t = base[3 * SSTR + p3]; if (t < hv) { hv = t; sm = 3; }
      t = base[4 * SSTR + p4]; if (t < hv) { hv = t; sm = 4; }
      t = base[5 * SSTR + p5]; if (t < hv) { hv = t; sm = 5; }
      t = base[6 * SSTR + p6]; if (t < hv) { hv = t; sm = 6; }
      t = base[7 * SSTR + p7]; if (t < hv) { hv = t; sm = 7; }
      crow[k] = __float_as_int(hv) & 0xFFF;
      p0 += (sm == 0); p1 += (sm == 1); p2 += (sm == 2); p3 += (sm == 3);
      p4 += (sm == 4); p5 += (sm == 5); p6 += (sm == 6); p7 += (sm == 7);
    }
  }
}

// ---------------- K3: fused refine + gather (8 rows/block, 512 threads) ----------------
// Refine phase = R19's proven refine (separate LDS arrays, flat barriers);
// nn stays in LDS; gather phase = R19's proven gather reading nnsh.
__global__ __launch_bounds__(512) void refgather_kernel(const float* __restrict__ x,
                                                        const int* __restrict__ cand,
                                                        const float* __restrict__ A,
                                                        const float* __restrict__ C,
                                                        const float* __restrict__ bias,
                                                        float* __restrict__ P,
                                                        float* __restrict__ Q,
                                                        float* __restrict__ sums) {
  __shared__ float  xs[8][64];
  __shared__ double ds[8][CAND];
  __shared__ int    jsm[8][CAND];
  __shared__ int    nnsh[8][K_];
  __shared__ float  red[8][2][O_];
  const int tid = threadIdx.x;
  const int rowbase = ((blockIdx.x & 7) << 12) + (blockIdx.x >> 3) * 8;
  const int b = rowbase >> 12;

  // --- refine phase (threads 0..255 active; barriers at top level) ---
  const int rw = tid >> 6, rlane = tid & 63;
  const int rhalf = rlane >> 5, rc = rlane & 31;
  const int rl = rw * 2 + rhalf;            // row within block 0..7 (for tid<256)

  if (tid < 128)
    *(float4*)&xs[tid >> 4][(tid & 15) * 4] =
        ((const float4*)(x + (size_t)(rowbase + (tid >> 4)) * F_))[tid & 15];
  __syncthreads();

  if (tid < 256 && rc < CAND) {
    int j = cand[(size_t)(rowbase + rl) * CAND + rc];
    const float4* xj4 = (const float4*)(x + ((size_t)(b << 12) + j) * F_);
    double s = 0.0;
#pragma unroll
    for (int u = 0; u < 16; ++u) {
      float4 a = *(const float4*)&xs[rl][u * 4];
      float4 v = xj4[u];
      double d0 = (double)a.x - (double)v.x;
      double d1 = (double)a.y - (double)v.y;
      double d2 = (double)a.z - (double)v.z;
      double d3 = (double)a.w - (double)v.w;
      s = fma(d0, d0, s); s = fma(d1, d1, s);
      s = fma(d2, d2, s); s = fma(d3, d3, s);
    }
    ds[rl][rc] = s; jsm[rl][rc] = j;
  }
  __syncthreads();
  if (tid < 256 && rc < CAND) {
    double dm = ds[rl][rc]; int jm = jsm[rl][rc];
    int rank = 0;
#pragma unroll
    for (int m = 0; m < CAND; ++m) {
      double dmm = ds[rl][m]; int jmm = jsm[rl][m];
      rank += (dmm < dm) || (dmm == dm && jmm < jm);
    }
    if (rank < K_) nnsh[rl][rank] = jm;
  }
  __syncthreads();

  // --- gather phase (all 512 threads): R19's gather with nrow from LDS ---
  const int w = tid >> 6;       // row 0..7
  const int o = tid & 63;       // channel
  const int rowg = rowbase + w;
  int4 j4[5];
#pragma unroll
  for (int u = 0; u < 5; ++u) j4[u] = ((const int4*)&nnsh[w][0])[u];
  float a = A[(size_t)rowg * O_ + o] + bias[o];
  float mxv = -FLT_MAX, mnv = FLT_MAX, s1 = 0.f, s2 = 0.f;
#pragma unroll
  for (int u = 0; u < 5; ++u) {
    int jj[4] = {j4[u].x, j4[u].y, j4[u].z, j4[u].w};
#pragma unroll
    for (int e = 0; e < 4; ++e) {
      float c = C[((size_t)(b << 12) + jj[e]) * O_ + o];
      mxv = fmaxf(mxv, c); mnv = fminf(mnv, c); s1 += c; s2 = fmaf(c, c, s2);
    }
  }
  P[(size_t)rowg * O_ + o] = a + mxv;
  Q[(size_t)rowg * O_ + o] = a + mnv;
  red[w][0][o] = 20.f * a + s1;
  red[w][1][o] = fmaf(20.f * a, a, fmaf(2.f * a, s1, s2));
  __syncthreads();
  if (w == 0) {
    float ts = 0.f, tq = 0.f;
#pragma unroll
    for (int u = 0; u < 8; ++u) { ts += red[u][0][o]; tq += red[u][1][o]; }
    atomicAdd(&sums[o], ts);
    atomicAdd(&sums[O_ + o], tq);
  }
}

// ---------------- K4: out — inline BN stats + normalize + relu ----------------
__global__ __launch_bounds__(256) void out_kernel(const float* __restrict__ P,
                                                  const float* __restrict__ Q,
                                                  const float* __restrict__ sums,
                                                  const float* __restrict__ gamma,
                                                  const float* __restrict__ beta,
                                                  float* __restrict__ out) {
  int gid = blockIdx.x * 256 + threadIdx.x;
  int o = gid & 63;
  const float cnt = (float)B_ * (float)N_ * (float)K_;
  float mean = sums[o] / cnt;
  float var = sums[O_ + o] / cnt - mean * mean;
  float s = gamma[o] / sqrtf(var + 1e-5f);
  float base = beta[o] - mean * s;
  float h = (s >= 0.f) ? P[gid] : Q[gid];
  float z = fmaf(h, s, base);
  out[gid] = z > 0.f ? z : 0.f;
}

extern "C" void kernel_launch(void* const* d_in, const int* in_sizes, int n_in,
                              void* d_out, int out_size, void* d_ws, size_t ws_size,
                              hipStream_t stream) {
  const float* x     = (const float*)d_in[0];
  const float* W     = (const float*)d_in[1];
  const float* bias  = (const float*)d_in[2];
  const float* gamma = (const float*)d_in[3];
  const float* beta  = (const float*)d_in[4];
  float* out = (float*)d_out;

  char* ws = (char*)d_ws;
  size_t off = 0;
  auto alloc = [&](size_t bytes) -> void* {
    void* p = ws + off;
    off += (bytes + 255) & ~(size_t)255;
    return p;
  };
  ushort* xhi  = (ushort*)alloc(sizeof(ushort) * (size_t)B_ * N_ * F_);
  float* sq    = (float*)alloc(sizeof(float) * (size_t)B_ * N_);
  int*   cand  = (int*)  alloc(sizeof(int)   * (size_t)B_ * N_ * CAND);
  float* A     = (float*)alloc(sizeof(float) * (size_t)B_ * N_ * O_);
  float* C     = (float*)alloc(sizeof(float) * (size_t)B_ * N_ * O_);
  float* P     = (float*)alloc(sizeof(float) * (size_t)B_ * N_ * O_);
  float* Q     = (float*)alloc(sizeof(float) * (size_t)B_ * N_ * O_);
  float* sums  = (float*)alloc(sizeof(float) * 2 * O_);

  feat_kernel     <<<(B_ * N_) / 16, 256, 0, stream>>>(x, W, A, C, xhi, sq, sums);
  knn_kernel      <<<B_ * (N_ / ITILE), 512, 0, stream>>>(xhi, sq, cand);
  refgather_kernel<<<(B_ * N_) / 8, 512, 0, stream>>>(x, cand, A, C, bias, P, Q, sums);
  out_kernel      <<<(B_ * N_ * O_) / 256, 256, 0, stream>>>(P, Q, sums, gamma, beta, out);
}

// Round 21
// 301.630 us; speedup vs baseline: 1.2313x; 1.2313x over previous
//
#include <hip/hip_runtime.h>
#include <cfloat>
#include <math.h>

#define B_ 8
#define N_ 4096
#define F_ 64
#define O_ 64
#define K_ 20
#define NSEL 20       // per-owner kept; NSEL >= K_ REQUIRED for exactness (R11 post-mortem)
#define CAND 24       // emitted after 8-way merge
#define NOWN 8
#define ITILE 64      // i-rows per block (co-residency invariant: grid 512, 2 blocks/CU)
#define JCH 128       // j-chunk per iteration
#define BSTR 72       // ushort stride of staged rows
#define QSTR 172      // rowq stride (==12 mod 32); >= 168 for sorted dump
#define SSTR 21       // sorted-dump stride per owner (20 + sentinel)

typedef __attribute__((ext_vector_type(8))) short bf16x8;
typedef __attribute__((ext_vector_type(16))) float f32x16;

__device__ __forceinline__ ushort f2bf(float f) {
  unsigned u = __float_as_uint(f);
  u += 0x7FFF + ((u >> 16) & 1);   // round-to-nearest-even
  return (ushort)(u >> 16);
}

// ---------------- K1: feat + fused bf16 convert + squared norms ----------------
__global__ __launch_bounds__(256) void feat_kernel(const float* __restrict__ x,
                                                   const float* __restrict__ W,
                                                   float* __restrict__ A,
                                                   float* __restrict__ C,
                                                   ushort* __restrict__ xhi,
                                                   float* __restrict__ sq) {
  __shared__ float xs[16][64];
  const int nb = blockIdx.x * 16;
  {
    int row = threadIdx.x >> 4, f4 = threadIdx.x & 15;
    float4 v = ((const float4*)(x + (size_t)(nb + row) * F_))[f4];
    *(float4*)&xs[row][f4 * 4] = v;
    ((ushort4*)(xhi + (size_t)(nb + row) * F_))[f4] =
        make_ushort4(f2bf(v.x), f2bf(v.y), f2bf(v.z), f2bf(v.w));
    float s = v.x * v.x + v.y * v.y + v.z * v.z + v.w * v.w;
#pragma unroll
    for (int off = 1; off < 16; off <<= 1) s += __shfl_xor(s, off, 64);
    if (f4 == 0) sq[nb + row] = s;
  }
  __syncthreads();
  const int o = threadIdx.x & 127;
  const int rgrp = threadIdx.x >> 7;
  if (o < O_) {
    float wd[64];
    const float4* w1 = (const float4*)(W + (size_t)o * 128);
    const float4* w2 = w1 + 16;
#pragma unroll
    for (int f = 0; f < 16; ++f) {
      float4 u = w1[f], v = w2[f];
      wd[4 * f] = u.x - v.x; wd[4 * f + 1] = u.y - v.y;
      wd[4 * f + 2] = u.z - v.z; wd[4 * f + 3] = u.w - v.w;
    }
#pragma unroll
    for (int r = 0; r < 8; ++r) {
      int row = rgrp * 8 + r;
      float a0 = 0.f, a1 = 0.f;
#pragma unroll
      for (int f = 0; f < 32; ++f) {
        a0 = fmaf(xs[row][2 * f], wd[2 * f], a0);
        a1 = fmaf(xs[row][2 * f + 1], wd[2 * f + 1], a1);
      }
      A[(size_t)(nb + row) * O_ + o] = a0 + a1;
    }
  } else {
    float wv[64];
    const float4* w2 = (const float4*)(W + (size_t)(o - O_) * 128 + 64);
#pragma unroll
    for (int f = 0; f < 16; ++f) {
      float4 v = w2[f];
      wv[4 * f] = v.x; wv[4 * f + 1] = v.y; wv[4 * f + 2] = v.z; wv[4 * f + 3] = v.w;
    }
#pragma unroll
    for (int r = 0; r < 8; ++r) {
      int row = rgrp * 8 + r;
      float a0 = 0.f, a1 = 0.f;
#pragma unroll
      for (int f = 0; f < 32; ++f) {
        a0 = fmaf(xs[row][2 * f], wv[2 * f], a0);
        a1 = fmaf(xs[row][2 * f + 1], wv[2 * f + 1], a1);
      }
      C[(size_t)(nb + row) * O_ + (o - O_)] = a0 + a1;
    }
  }
}

// ---------------- K2: kNN — byte-identical to R19 (measured 170 us) ----------------
struct KnnSh {
  ushort bhi[JCH][BSTR];      // 18432 B
  float  sqj[JCH];            // 512 B
  float  rowq[ITILE * QSTR];  // 44032 B
  int qcnt[ITILE];
  alignas(16) int thr[ITILE]; // 16B-aligned for b128 hoist
};                            // ~63.5 KB -> 2 blocks/CU (all 512 blocks co-resident)

__global__ __launch_bounds__(512, 4) void knn_kernel(const ushort* __restrict__ xhi,
                                                     const float* __restrict__ sq,
                                                     int* __restrict__ cand) {
  __shared__ KnnSh S;

  const int b = blockIdx.x >> 6;             // L2-proven mapping
  const int ib = (blockIdx.x & 63) * ITILE;  // batch-local i base
  const int tid = threadIdx.x;
  const int w = tid >> 6, lane = tid & 63;
  const int l31 = lane & 31, lh = lane >> 5;
  const int h = w & 1;                       // i-half
  const int jcol = (w >> 1) * 32;            // j-quarter

  bf16x8 ah[4];
  {
    const size_t ar = ((size_t)b * N_ + ib + h * 32 + l31) * F_ + lh * 8;
#pragma unroll
    for (int kk = 0; kk < 4; ++kk) ah[kk] = *(const bf16x8*)(xhi + ar + kk * 16);
  }
  float sqi[16];
#pragma unroll
  for (int r = 0; r < 16; ++r)
    sqi[r] = sq[b * N_ + ib + h * 32 + (r & 3) + 8 * (r >> 2) + 4 * lh];

  if (tid < ITILE) S.thr[tid] = 0x7F7F0000;

  const int orow = tid >> 3, oslot = tid & 7;   // 8 owners per row
  float d[NSEL];
#pragma unroll
  for (int k = 0; k < NSEL; ++k) d[k] = __int_as_float(0x7F7E0000 | k);
  float mx = __int_as_float(0x7F7E0000 | (NSEL - 1));

  const int selfchunk = ib & ~(JCH - 1);

  for (int jt = 0; jt < N_; jt += JCH) {
    __syncthreads();   // prev owner phase done; thr updates visible
    const bool dense = (jt < 2 * JCH);
    if (tid < ITILE) S.qcnt[tid] = dense ? JCH : 0;

    int4 thrq[4];
#pragma unroll
    for (int g = 0; g < 4; ++g)
      thrq[g] = *(const int4*)&S.thr[h * 32 + 4 * lh + 8 * g];

#pragma unroll
    for (int u = 0; u < 2; ++u) {
      int idx = tid + u * 512;
      int jr = idx >> 3, fc = (idx & 7) * 8;
      *(bf16x8*)&S.bhi[jr][fc] =
          *(const bf16x8*)(xhi + ((size_t)b * N_ + jt + jr) * F_ + fc);
    }
    if (tid < JCH) S.sqj[tid] = sq[b * N_ + jt + tid];
    __syncthreads();

    const ushort* bp = &S.bhi[jcol + l31][lh * 8];
    bf16x8 bf[4];
#pragma unroll
    for (int kk = 0; kk < 4; ++kk) bf[kk] = *(const bf16x8*)(bp + kk * 16);

    const int jg = jt + jcol + l31;              // batch-local j
    const float sqjv = S.sqj[jcol + l31];
    const bool selfc = (jt == selfchunk);

    f32x16 c = {0.f, 0.f, 0.f, 0.f, 0.f, 0.f, 0.f, 0.f,
                0.f, 0.f, 0.f, 0.f, 0.f, 0.f, 0.f, 0.f};
#pragma unroll
    for (int kk = 0; kk < 4; ++kk)
      c = __builtin_amdgcn_mfma_f32_32x32x16_bf16(ah[kk], bf[kk], c, 0, 0, 0);
#pragma unroll
    for (int r = 0; r < 16; ++r) {
      const int ir = h * 32 + (r & 3) + 8 * (r >> 2) + 4 * lh;  // local i-row
      float dd = fmaf(-2.f, c[r], sqi[r] + sqjv);
      float pv = __int_as_float((__float_as_int(dd) & (int)0xFFFFF000) | jg);
      if (selfc && (ib + ir == jg)) pv = __int_as_float(0x7F500000 | jg);
      if (dense) {
        S.rowq[ir * QSTR + (jcol + l31)] = pv;
      } else if (pv < __int_as_float(((const int*)&thrq[r >> 2])[r & 3])) {
        int pos = atomicAdd(&S.qcnt[ir], 1);
        S.rowq[ir * QSTR + pos] = pv;
      }
    }
    __syncthreads();

    {
      int cn = S.qcnt[orow];
      for (int q = oslot; q < cn; q += NOWN) {
        float pv = S.rowq[orow * QSTR + q];
        if (pv < mx) {
#pragma unroll
          for (int k = 0; k < NSEL; ++k) d[k] = (d[k] == mx) ? pv : d[k];
          float t0[10];
#pragma unroll
          for (int k = 0; k < 10; ++k) t0[k] = fmaxf(d[2 * k], d[2 * k + 1]);
#pragma unroll
          for (int k = 0; k < 5; ++k) t0[k] = fmaxf(t0[2 * k], (k < 4) ? t0[2 * k + 1] : t0[9]);
          mx = fmaxf(fmaxf(fmaxf(t0[0], t0[1]), fmaxf(t0[2], t0[3])), t0[4]);
        }
      }
      atomicMin(&S.thr[orow], __float_as_int(mx));
    }
  }

  __syncthreads();  // queue dead; reuse rowq for sorted dump
  float a32[32];
#pragma unroll
  for (int k = 0; k < NSEL; ++k) a32[k] = d[k];
#pragma unroll
  for (int k = NSEL; k < 32; ++k) a32[k] = __int_as_float(0x7F7E0000 | k);
#pragma unroll
  for (int kk = 2; kk <= 32; kk <<= 1) {
#pragma unroll
    for (int jj = kk >> 1; jj > 0; jj >>= 1) {
#pragma unroll
      for (int ii = 0; ii < 32; ++ii) {
        int ll = ii ^ jj;
        if (ll > ii) {
          bool up = ((ii & kk) == 0);
          float av = a32[ii], bv = a32[ll];
          float lo = fminf(av, bv), hi = fmaxf(av, bv);
          a32[ii] = up ? lo : hi;
          a32[ll] = up ? hi : lo;
        }
      }
    }
  }
#pragma unroll
  for (int k = 0; k < NSEL; ++k)
    S.rowq[orow * QSTR + oslot * SSTR + k] = a32[k];
  S.rowq[orow * QSTR + oslot * SSTR + NSEL] = __int_as_float(0x7F700000);
  __syncthreads();

  if (tid < ITILE) {
    const float* base = &S.rowq[tid * QSTR];
    int* crow = cand + (size_t)(b * N_ + ib + tid) * CAND;
    int p0 = 0, p1 = 0, p2 = 0, p3 = 0, p4 = 0, p5 = 0, p6 = 0, p7 = 0;
    for (int k = 0; k < CAND; ++k) {
      float hv = base[p0]; int sm = 0;
      float t;
      t = base[SSTR + p1];     if (t < hv) { hv = t; sm = 1; }
      t = base[2 * SSTR + p2]; if (t < hv) { hv = t; sm = 2; }
      t = base[3 * SSTR + p3]; if (t < hv) { hv = t; sm = 3; }
      t = base[4 * SSTR + p4]; if (t < hv) { hv = t; sm = 4; }
      t = base[5 * SSTR + p5]; if (t < hv) { hv = t; sm = 5; }
      t = base[6 * SSTR + p6]; if (t < hv) { hv = t; sm = 6; }
      t = base[7 * SSTR + p7]; if (t < hv) { hv = t; sm = 7; }
      crow[k] = __float_as_int(hv) & 0xFFF;
      p0 += (sm == 0); p1 += (sm == 1); p2 += (sm == 2); p3 += (sm == 3);
      p4 += (sm == 4); p5 += (sm == 5); p6 += (sm == 6); p7 += (sm == 7);
    }
  }
}

// ---------------- K3: fused refine + gather -> per-block partials (NO atomics) ----------------
__global__ __launch_bounds__(512) void refgather_kernel(const float* __restrict__ x,
                                                        const int* __restrict__ cand,
                                                        const float* __restrict__ A,
                                                        const float* __restrict__ C,
                                                        const float* __restrict__ bias,
                                                        float* __restrict__ P,
                                                        float* __restrict__ Q,
                                                        float* __restrict__ partial) {
  __shared__ float  xs[8][64];
  __shared__ double ds[8][CAND];
  __shared__ int    jsm[8][CAND];
  __shared__ int    nnsh[8][K_];
  __shared__ float  red[8][2][O_];
  const int tid = threadIdx.x;
  const int rowbase = ((blockIdx.x & 7) << 12) + (blockIdx.x >> 3) * 8;
  const int b = rowbase >> 12;

  // --- refine phase (threads 0..255 active; barriers at top level) ---
  const int rw = tid >> 6, rlane = tid & 63;
  const int rhalf = rlane >> 5, rc = rlane & 31;
  const int rl = rw * 2 + rhalf;            // row within block 0..7 (for tid<256)

  if (tid < 128)
    *(float4*)&xs[tid >> 4][(tid & 15) * 4] =
        ((const float4*)(x + (size_t)(rowbase + (tid >> 4)) * F_))[tid & 15];
  __syncthreads();

  if (tid < 256 && rc < CAND) {
    int j = cand[(size_t)(rowbase + rl) * CAND + rc];
    const float4* xj4 = (const float4*)(x + ((size_t)(b << 12) + j) * F_);
    double s = 0.0;
#pragma unroll
    for (int u = 0; u < 16; ++u) {
      float4 a = *(const float4*)&xs[rl][u * 4];
      float4 v = xj4[u];
      double d0 = (double)a.x - (double)v.x;
      double d1 = (double)a.y - (double)v.y;
      double d2 = (double)a.z - (double)v.z;
      double d3 = (double)a.w - (double)v.w;
      s = fma(d0, d0, s); s = fma(d1, d1, s);
      s = fma(d2, d2, s); s = fma(d3, d3, s);
    }
    ds[rl][rc] = s; jsm[rl][rc] = j;
  }
  __syncthreads();
  if (tid < 256 && rc < CAND) {
    double dm = ds[rl][rc]; int jm = jsm[rl][rc];
    int rank = 0;
#pragma unroll
    for (int m = 0; m < CAND; ++m) {
      double dmm = ds[rl][m]; int jmm = jsm[rl][m];
      rank += (dmm < dm) || (dmm == dm && jmm < jm);
    }
    if (rank < K_) nnsh[rl][rank] = jm;
  }
  __syncthreads();

  // --- gather phase (all 512 threads): R19's gather with nrow from LDS ---
  const int w = tid >> 6;       // row 0..7
  const int o = tid & 63;       // channel
  const int rowg = rowbase + w;
  int4 j4[5];
#pragma unroll
  for (int u = 0; u < 5; ++u) j4[u] = ((const int4*)&nnsh[w][0])[u];
  float a = A[(size_t)rowg * O_ + o] + bias[o];
  float mxv = -FLT_MAX, mnv = FLT_MAX, s1 = 0.f, s2 = 0.f;
#pragma unroll
  for (int u = 0; u < 5; ++u) {
    int jj[4] = {j4[u].x, j4[u].y, j4[u].z, j4[u].w};
#pragma unroll
    for (int e = 0; e < 4; ++e) {
      float c = C[((size_t)(b << 12) + jj[e]) * O_ + o];
      mxv = fmaxf(mxv, c); mnv = fminf(mnv, c); s1 += c; s2 = fmaf(c, c, s2);
    }
  }
  P[(size_t)rowg * O_ + o] = a + mxv;
  Q[(size_t)rowg * O_ + o] = a + mnv;
  red[w][0][o] = 20.f * a + s1;
  red[w][1][o] = fmaf(20.f * a, a, fmaf(2.f * a, s1, s2));
  __syncthreads();
  if (w == 0) {
    float ts = 0.f, tq = 0.f;
#pragma unroll
    for (int u = 0; u < 8; ++u) { ts += red[u][0][o]; tq += red[u][1][o]; }
    partial[(size_t)blockIdx.x * 128 + o] = ts;
    partial[(size_t)blockIdx.x * 128 + 64 + o] = tq;
  }
}

// ---------------- K4: coalesced partial reduction (stage 1, 4096 rows) ----------------
__global__ __launch_bounds__(256) void reduce1_kernel(const float* __restrict__ partial,
                                                      float* __restrict__ partial2) {
  __shared__ float red[2][128];
  int c = threadIdx.x & 127, rq = threadIdx.x >> 7;
  int base = blockIdx.x * 64;
  float s = 0.f;
  for (int i = 0; i < 32; ++i)
    s += partial[(size_t)(base + rq + 2 * i) * 128 + c];
  red[rq][c] = s;
  __syncthreads();
  if (rq == 0) partial2[(size_t)blockIdx.x * 128 + c] = red[0][c] + red[1][c];
}

// ---------------- K5: stage-2 reduce + finalize BN stats ----------------
__global__ void stats_kernel(const float* __restrict__ partial2,
                             const float* __restrict__ gamma,
                             const float* __restrict__ beta,
                             float* __restrict__ sb) {
  __shared__ float sall[128];
  int c = threadIdx.x;
  float s = 0.f;
  for (int blk = 0; blk < 64; ++blk) s += partial2[(size_t)blk * 128 + c];
  sall[c] = s;
  __syncthreads();
  if (c < 64) {
    const float cnt = (float)B_ * (float)N_ * (float)K_;
    float mean = sall[c] / cnt;
    float var = sall[64 + c] / cnt - mean * mean;
    float sc = gamma[c] / sqrtf(var + 1e-5f);
    sb[c] = sc;
    sb[64 + c] = beta[c] - mean * sc;
  }
}

// ---------------- K6: normalize + relu ----------------
__global__ __launch_bounds__(256) void out_kernel(const float* __restrict__ P,
                                                  const float* __restrict__ Q,
                                                  const float* __restrict__ sb,
                                                  float* __restrict__ out) {
  int gid = blockIdx.x * 256 + threadIdx.x;
  int o = gid & 63;
  float s = sb[o], base = sb[O_ + o];
  float h = (s >= 0.f) ? P[gid] : Q[gid];
  float z = fmaf(h, s, base);
  out[gid] = z > 0.f ? z : 0.f;
}

extern "C" void kernel_launch(void* const* d_in, const int* in_sizes, int n_in,
                              void* d_out, int out_size, void* d_ws, size_t ws_size,
                              hipStream_t stream) {
  const float* x     = (const float*)d_in[0];
  const float* W     = (const float*)d_in[1];
  const float* bias  = (const float*)d_in[2];
  const float* gamma = (const float*)d_in[3];
  const float* beta  = (const float*)d_in[4];
  float* out = (float*)d_out;

  char* ws = (char*)d_ws;
  size_t off = 0;
  auto alloc = [&](size_t bytes) -> void* {
    void* p = ws + off;
    off += (bytes + 255) & ~(size_t)255;
    return p;
  };
  ushort* xhi     = (ushort*)alloc(sizeof(ushort) * (size_t)B_ * N_ * F_);
  float* sq       = (float*)alloc(sizeof(float) * (size_t)B_ * N_);
  int*   cand     = (int*)  alloc(sizeof(int)   * (size_t)B_ * N_ * CAND);
  float* A        = (float*)alloc(sizeof(float) * (size_t)B_ * N_ * O_);
  float* C        = (float*)alloc(sizeof(float) * (size_t)B_ * N_ * O_);
  float* P        = (float*)alloc(sizeof(float) * (size_t)B_ * N_ * O_);
  float* Q        = (float*)alloc(sizeof(float) * (size_t)B_ * N_ * O_);
  float* partial  = (float*)alloc(sizeof(float) * 4096 * 128);
  float* partial2 = (float*)alloc(sizeof(float) * 64 * 128);
  float* sb       = (float*)alloc(sizeof(float) * 2 * O_);

  feat_kernel     <<<(B_ * N_) / 16, 256, 0, stream>>>(x, W, A, C, xhi, sq);
  knn_kernel      <<<B_ * (N_ / ITILE), 512, 0, stream>>>(xhi, sq, cand);
  refgather_kernel<<<(B_ * N_) / 8, 512, 0, stream>>>(x, cand, A, C, bias, P, Q, partial);
  reduce1_kernel  <<<64, 256, 0, stream>>>(partial, partial2);
  stats_kernel    <<<1, 128, 0, stream>>>(partial2, gamma, beta, sb);
  out_kernel      <<<(B_ * N_ * O_) / 256, 256, 0, stream>>>(P, Q, sb, out);
}